// Round 9
// baseline (5612.049 us; speedup 1.0000x reference)
//
#include <hip/hip_runtime.h>
#include <hip/hip_fp16.h>

#define NN 100000
#define NPAD 100096   // 64*1564
#define EE 3200000
#define HH 128
#define CC 40

typedef _Float16 f16x8 __attribute__((ext_vector_type(8)));
typedef float f32x4 __attribute__((ext_vector_type(4)));

#define EDEC_W(v) ((float)((v) >> 17) * (1.f / 32767.f))
#define EDEC_S(v) ((v) & 131071u)

// tanh(x) = (e^2x - 1)/(e^2x + 1); clamp avoids inf*0=NaN. ~6 VALU ops.
__device__ __forceinline__ float fast_tanh(float x) {
    float t = __expf(2.f * fminf(x, 15.f));
    return (t - 1.f) * __builtin_amdgcn_rcpf(t + 1.f);
}

// rp[i] = lower_bound(edge_dst, i) — edge_dst is sorted.
__global__ void build_rp(const int* __restrict__ dst, int* __restrict__ rp) {
    int i = blockIdx.x * blockDim.x + threadIdx.x;
    if (i > NN) return;
    int lo = 0, hi = EE;
    while (lo < hi) {
        int mid = (lo + hi) >> 1;
        if (dst[mid] < i) lo = mid + 1; else hi = mid;
    }
    rp[i] = lo;
}

// prep: x->fp16; edges packed to 4B (src 17b | w 15b, for spmm40); weights fp16^T.
__global__ __launch_bounds__(256) void prep_all(const float* __restrict__ x,
                                                const int* __restrict__ src,
                                                const float* __restrict__ w,
                                                const float* __restrict__ W0,
                                                const float* __restrict__ W1,
                                                const float* __restrict__ W2,
                                                __half* __restrict__ xh,
                                                unsigned* __restrict__ ewp,
                                                __half* __restrict__ W0t,
                                                __half* __restrict__ W1t,
                                                __half* __restrict__ W2t) {
    int b = blockIdx.x, tid = threadIdx.x;
    if (b < 6250) {                       // x: 12.8M elems, 8/thread
        int base = (b * 256 + tid) * 8;
        float4 a = *(const float4*)(x + base);
        float4 c = *(const float4*)(x + base + 4);
        __half2 h[4];
        h[0] = __floats2half2_rn(a.x, a.y);
        h[1] = __floats2half2_rn(a.z, a.w);
        h[2] = __floats2half2_rn(c.x, c.y);
        h[3] = __floats2half2_rn(c.z, c.w);
        *(float4*)(xh + base) = *(float4*)h;
    } else if (b < 9375) {                // pack 4 edges/thread (spmm40 meta)
        int i = (b - 6250) * 256 + tid;   // < 800000
        int4 s = ((const int4*)src)[i];
        float4 f = ((const float4*)w)[i];
        uint4 p;
        p.x = (unsigned)s.x | ((unsigned)(f.x * 32767.f + 0.5f) << 17);
        p.y = (unsigned)s.y | ((unsigned)(f.y * 32767.f + 0.5f) << 17);
        p.z = (unsigned)s.z | ((unsigned)(f.z * 32767.f + 0.5f) << 17);
        p.w = (unsigned)s.w | ((unsigned)(f.w * 32767.f + 0.5f) << 17);
        ((uint4*)ewp)[i] = p;
    } else {                              // W0t,W1t [128][128]; W2t [64][128]
        int i = (b - 9375) * 256 + tid;
        if (i < HH * HH) {
            int c = i >> 7, k = i & 127;
            W0t[i] = __float2half_rn(W0[k * HH + c]);
            W1t[i] = __float2half_rn(W1[k * HH + c]);
        }
        if (i < 64 * HH) {
            int c = i >> 7, k = i & 127;
            W2t[i] = __float2half_rn(c < CC ? W2[k * CC + c] : 0.f);
        }
    }
}

// Bucket each 128-node block's edges by src-tile (src>>12, 1MB of h each).
// Order within a tile is irrelevant (segment-sum commutes). 8B meta:
// word0 = src | dst_local<<17, word1 = w (f32, exact).
__global__ __launch_bounds__(256) void sort8(const int* __restrict__ src,
                                             const int* __restrict__ dst,
                                             const float* __restrict__ w,
                                             const int* __restrict__ rp,
                                             uint2* __restrict__ outp) {
    __shared__ int hist[32];
    __shared__ int cur[32];
    int n0 = blockIdx.x * 128;
    int nend = n0 + 128 < NN ? n0 + 128 : NN;
    int e0 = rp[n0], e1 = rp[nend], m = e1 - e0;
    int tid = threadIdx.x;
    if (tid < 32) hist[tid] = 0;
    __syncthreads();
    for (int i = tid; i < m; i += 256)
        atomicAdd(&hist[src[e0 + i] >> 12], 1);
    __syncthreads();
    if (tid == 0) {
        int run = 0;
        for (int t = 0; t < 32; ++t) { cur[t] = run; run += hist[t]; }
    }
    __syncthreads();
    for (int i = tid; i < m; i += 256) {
        int s = src[e0 + i];
        int rank = atomicAdd(&cur[s >> 12], 1);
        uint2 o;
        o.x = (unsigned)s | ((unsigned)(dst[e0 + i] - n0) << 17);
        o.y = __float_as_int(w[e0 + i]);
        outp[e0 + rank] = o;
    }
}

// 2D-blocked spmm: block = 128 dst nodes, LDS f32 accumulators.
// Edges tile-sorted; 8 waves walk the list interleaved (stride 8 over
// 16-edge groups) so all waves stay in the same ~1MB src-tile -> L2 hits.
__global__ __launch_bounds__(512) void spmm_lds(const __half* __restrict__ h,
                                                const uint2* __restrict__ ews,
                                                const int* __restrict__ rp,
                                                __half* __restrict__ out) {
    __shared__ float acc[128][132];
    int tid = threadIdx.x;
    int n0 = blockIdx.x * 128;
    for (int i = tid; i < 128 * 132; i += 512) ((float*)acc)[i] = 0.f;
    __syncthreads();
    int nend = n0 + 128 < NN ? n0 + 128 : NN;
    int e0 = __builtin_amdgcn_readfirstlane(rp[n0]);
    int e1 = __builtin_amdgcn_readfirstlane(rp[nend]);
    int m = e1 - e0;
    int wave = tid >> 6, l = tid & 63, g = l >> 4, r = l & 15;
    const f16x8* __restrict__ hrow = (const f16x8*)h;
    int G = (m + 15) >> 4;                // 16-edge groups
    for (int gi = wave; gi < G; gi += 8) {
        int eb = e0 + gi * 16;
        int i0 = eb + g, i1 = eb + 4 + g, i2 = eb + 8 + g, i3 = eb + 12 + g;
        bool v0 = i0 < e1, v1 = i1 < e1, v2 = i2 < e1, v3 = i3 < e1;
        uint2 m0 = ews[v0 ? i0 : e0];
        uint2 m1 = ews[v1 ? i1 : e0];
        uint2 m2 = ews[v2 ? i2 : e0];
        uint2 m3 = ews[v3 ? i3 : e0];
        f16x8 a0 = hrow[(size_t)(m0.x & 131071u) * 16 + r];
        f16x8 a1 = hrow[(size_t)(m1.x & 131071u) * 16 + r];
        f16x8 a2 = hrow[(size_t)(m2.x & 131071u) * 16 + r];
        f16x8 a3 = hrow[(size_t)(m3.x & 131071u) * 16 + r];
        int d0 = (m0.x >> 17) & 127, d1 = (m1.x >> 17) & 127;
        int d2 = (m2.x >> 17) & 127, d3 = (m3.x >> 17) & 127;
        float w0 = v0 ? __int_as_float(m0.y) : 0.f;
        float w1 = v1 ? __int_as_float(m1.y) : 0.f;
        float w2 = v2 ? __int_as_float(m2.y) : 0.f;
        float w3 = v3 ? __int_as_float(m3.y) : 0.f;
#pragma unroll
        for (int j = 0; j < 8; ++j) atomicAdd(&acc[d0][r * 8 + j], w0 * (float)a0[j]);
#pragma unroll
        for (int j = 0; j < 8; ++j) atomicAdd(&acc[d1][r * 8 + j], w1 * (float)a1[j]);
#pragma unroll
        for (int j = 0; j < 8; ++j) atomicAdd(&acc[d2][r * 8 + j], w2 * (float)a2[j]);
#pragma unroll
        for (int j = 0; j < 8; ++j) atomicAdd(&acc[d3][r * 8 + j], w3 * (float)a3[j]);
    }
    __syncthreads();
    int row = tid >> 2, c0 = (tid & 3) * 32;   // 4 threads/row, 32 feats each
    if (n0 + row < NN) {
        _Float16* op = (_Float16*)out + (size_t)(n0 + row) * HH + c0;
#pragma unroll
        for (int b = 0; b < 4; ++b) {
            f16x8 v;
#pragma unroll
            for (int j = 0; j < 8; ++j) v[j] = (_Float16)acc[row][c0 + b * 8 + j];
            *(f16x8*)(op + b * 8) = v;
        }
    }
}

// Layer 3: out = tanh(spmm(g)); g rows padded to 64 halves (128B). 8 lanes/row.
__global__ __launch_bounds__(256) void spmm40_tanh(const __half* __restrict__ gpad,
                                                   const unsigned* __restrict__ ewp,
                                                   const int* __restrict__ rp,
                                                   float* __restrict__ out) {
    int node = blockIdx.x * 4 + (threadIdx.x >> 6);
    int l = threadIdx.x & 63;
    if (node >= NN) return;
    int e0 = __builtin_amdgcn_readfirstlane(rp[node]);
    int e1 = __builtin_amdgcn_readfirstlane(rp[node + 1]);
    int g = l >> 3, r = l & 7;
    const f16x8* __restrict__ grw = (const f16x8*)gpad;
    float acc[8] = {};
    int e = e0;
    while ((e & 1) && e < e1) {           // peel to 8B alignment
        unsigned v = ewp[e];
        float wk = (g == 0) ? EDEC_W(v) : 0.f;
        f16x8 vv = grw[(size_t)EDEC_S(v) * 8 + r];
#pragma unroll
        for (int j = 0; j < 8; ++j) acc[j] = fmaf(wk, (float)vv[j], acc[j]);
        ++e;
    }
    int e16 = e + ((e1 - e) & ~15);
    for (; e < e16; e += 16) {            // group g owns edges e+2g, e+2g+1
        uint2 pa = *(const uint2*)(ewp + e + 2 * g);
        f16x8 v0 = grw[(size_t)EDEC_S(pa.x) * 8 + r];
        f16x8 v1 = grw[(size_t)EDEC_S(pa.y) * 8 + r];
        float w0 = EDEC_W(pa.x), w1 = EDEC_W(pa.y);
#pragma unroll
        for (int j = 0; j < 8; ++j) acc[j] = fmaf(w0, (float)v0[j], acc[j]);
#pragma unroll
        for (int j = 0; j < 8; ++j) acc[j] = fmaf(w1, (float)v1[j], acc[j]);
    }
    if (e < e1) {                         // masked tail (<16 edges)
#pragma unroll
        for (int k = 0; k < 2; ++k) {
            int idx = e + 2 * g + k;
            bool val = idx < e1;
            unsigned v = ewp[val ? idx : e0];
            float wk = val ? EDEC_W(v) : 0.f;
            f16x8 vv = grw[(size_t)EDEC_S(v) * 8 + r];
#pragma unroll
            for (int j = 0; j < 8; ++j) acc[j] = fmaf(wk, (float)vv[j], acc[j]);
        }
    }
#pragma unroll
    for (int j = 0; j < 8; ++j) {
        acc[j] += __shfl_xor(acc[j], 8);
        acc[j] += __shfl_xor(acc[j], 16);
        acc[j] += __shfl_xor(acc[j], 32);
    }
    if (l < 5) {
        float o[8];
#pragma unroll
        for (int j = 0; j < 8; ++j) o[j] = fast_tanh(acc[j]);
        *(float4*)(out + (size_t)node * CC + r * 8) = *(float4*)&o[0];
        *(float4*)(out + (size_t)node * CC + r * 8 + 4) = *(float4*)&o[4];
    }
}

// Layer-1 GEMM: out = tanh(A @ W) fp16, epilogue coalesced via LDS.
__global__ __launch_bounds__(256) void gemm_tanh_mfma(const __half* __restrict__ A,
                                                      const __half* __restrict__ Wt,
                                                      __half* __restrict__ out) {
    __shared__ _Float16 st[4][16][136];
    int wave = threadIdx.x >> 6, l = threadIdx.x & 63;
    int r0 = blockIdx.x * 64 + wave * 16;
    int lr = l & 15, lg = l >> 4;
    const _Float16* Af = (const _Float16*)A;
    const _Float16* Wf = (const _Float16*)Wt;
    f16x8 a[4];
#pragma unroll
    for (int kb = 0; kb < 4; ++kb)
        a[kb] = *(const f16x8*)(Af + (size_t)(r0 + lr) * HH + kb * 32 + lg * 8);
#pragma unroll
    for (int ct = 0; ct < 8; ++ct) {
        f32x4 acc = {0.f, 0.f, 0.f, 0.f};
#pragma unroll
        for (int kb = 0; kb < 4; ++kb) {
            f16x8 b = *(const f16x8*)(Wf + (size_t)(ct * 16 + lr) * HH + kb * 32 + lg * 8);
            acc = __builtin_amdgcn_mfma_f32_16x16x32_f16(a[kb], b, acc, 0, 0, 0);
        }
#pragma unroll
        for (int r = 0; r < 4; ++r)
            st[wave][lg * 4 + r][ct * 16 + lr] = (_Float16)fast_tanh(acc[r]);
    }
#pragma unroll
    for (int i = 0; i < 4; ++i) {
        int row = lg + 4 * i;
        int grow = r0 + row;
        f16x8 v = *(const f16x8*)&st[wave][row][lr * 8];
        if (grow < NN)
            *(f16x8*)((_Float16*)out + (size_t)grow * HH + lr * 8) = v;
    }
}

// Layer-2 fused: h2 = tanh(A @ W1) (LDS only), g = h2 @ W2 -> gout [NPAD][64] fp16.
__global__ __launch_bounds__(256) void gemm2_fused(const __half* __restrict__ A,
                                                   const __half* __restrict__ W1t,
                                                   const __half* __restrict__ W2t,
                                                   __half* __restrict__ gout) {
    __shared__ _Float16 st[4][16][136];
    int wave = threadIdx.x >> 6, l = threadIdx.x & 63;
    int r0 = blockIdx.x * 64 + wave * 16;
    int lr = l & 15, lg = l >> 4;
    const _Float16* Af = (const _Float16*)A;
    const _Float16* W1f = (const _Float16*)W1t;
    const _Float16* W2f = (const _Float16*)W2t;
    f16x8 a[4];
#pragma unroll
    for (int kb = 0; kb < 4; ++kb)
        a[kb] = *(const f16x8*)(Af + (size_t)(r0 + lr) * HH + kb * 32 + lg * 8);
#pragma unroll
    for (int ct = 0; ct < 8; ++ct) {
        f32x4 acc = {0.f, 0.f, 0.f, 0.f};
#pragma unroll
        for (int kb = 0; kb < 4; ++kb) {
            f16x8 b = *(const f16x8*)(W1f + (size_t)(ct * 16 + lr) * HH + kb * 32 + lg * 8);
            acc = __builtin_amdgcn_mfma_f32_16x16x32_f16(a[kb], b, acc, 0, 0, 0);
        }
#pragma unroll
        for (int r = 0; r < 4; ++r)
            st[wave][lg * 4 + r][ct * 16 + lr] = (_Float16)fast_tanh(acc[r]);
    }
    f16x8 a2[4];
#pragma unroll
    for (int kb = 0; kb < 4; ++kb)
        a2[kb] = *(const f16x8*)&st[wave][lr][kb * 32 + lg * 8];
#pragma unroll
    for (int ct = 0; ct < 4; ++ct) {
        f32x4 acc = {0.f, 0.f, 0.f, 0.f};
#pragma unroll
        for (int kb = 0; kb < 4; ++kb) {
            f16x8 b = *(const f16x8*)(W2f + (size_t)(ct * 16 + lr) * HH + kb * 32 + lg * 8);
            acc = __builtin_amdgcn_mfma_f32_16x16x32_f16(a2[kb], b, acc, 0, 0, 0);
        }
#pragma unroll
        for (int r = 0; r < 4; ++r)
            st[wave][lg * 4 + r][ct * 16 + lr] = (_Float16)acc[r];
    }
#pragma unroll
    for (int i = 0; i < 2; ++i) {
        int row = (l >> 3) + 8 * i;
        int grow = r0 + row;
        f16x8 v = *(const f16x8*)&st[wave][row][(l & 7) * 8];
        if (grow < NN)
            *(f16x8*)((_Float16*)gout + (size_t)grow * 64 + (l & 7) * 8) = v;
    }
}

extern "C" void kernel_launch(void* const* d_in, const int* in_sizes, int n_in,
                              void* d_out, int out_size, void* d_ws, size_t ws_size,
                              hipStream_t stream) {
    const float* x    = (const float*)d_in[0];
    const int*   esrc = (const int*)d_in[1];
    const int*   edst = (const int*)d_in[2];
    const float* ew_f = (const float*)d_in[3];
    const float* W0   = (const float*)d_in[4];
    const float* W1   = (const float*)d_in[5];
    const float* W2   = (const float*)d_in[6];
    float* out = (float*)d_out;

    char* ws = (char*)d_ws;
    size_t off = 0;
    int* rp = (int*)(ws + off);            off += (((size_t)(NN + 1) * 4) + 511) & ~(size_t)511;
    __half* buf0 = (__half*)(ws + off);    off += (size_t)NPAD * HH * sizeof(__half); // xh, later g
    __half* sA = (__half*)(ws + off);      off += (size_t)NPAD * HH * sizeof(__half);
    __half* hb = (__half*)(ws + off);      off += (size_t)NPAD * HH * sizeof(__half);
    unsigned* ewp = (unsigned*)(ws + off); off += (size_t)EE * sizeof(unsigned);      // spmm40 meta
    uint2* ews8 = (uint2*)(ws + off);      off += (size_t)EE * sizeof(uint2);         // tile-sorted 8B meta
    __half* W0t = (__half*)(ws + off);     off += (size_t)HH * HH * sizeof(__half);
    __half* W1t = (__half*)(ws + off);     off += (size_t)HH * HH * sizeof(__half);
    __half* W2t = (__half*)(ws + off);     off += (size_t)64 * HH * sizeof(__half);
    __half* xh = buf0;
    __half* gb = buf0;  // alias: xh dead after first spmm

    int nblk = (NN + 127) / 128;  // 782

    build_rp<<<(NN + 256) / 256, 256, 0, stream>>>(edst, rp);
    prep_all<<<9440, 256, 0, stream>>>(x, esrc, ew_f, W0, W1, W2,
                                       xh, ewp, W0t, W1t, W2t);
    sort8<<<nblk, 256, 0, stream>>>(esrc, edst, ew_f, rp, ews8);

    int gemm_grid = NPAD / 64;
    // layer 1
    spmm_lds<<<nblk, 512, 0, stream>>>(xh, ews8, rp, sA);
    gemm_tanh_mfma<<<gemm_grid, 256, 0, stream>>>(sA, W0t, hb);
    // layer 2 + output projection fused (h2 never hits global)
    spmm_lds<<<nblk, 512, 0, stream>>>(hb, ews8, rp, sA);
    gemm2_fused<<<gemm_grid, 256, 0, stream>>>(sA, W1t, W2t, gb);
    // layer 3: out = tanh(spmm(g))
    spmm40_tanh<<<NN / 4, 256, 0, stream>>>(gb, ewp, rp, out);
}

// Round 10
// 435.656 us; speedup vs baseline: 12.8818x; 12.8818x over previous
//
#include <hip/hip_runtime.h>
#include <hip/hip_fp16.h>

#define NN 100000
#define EE 3200000
#define HH 128
#define CC 40

typedef _Float16 f16x8 __attribute__((ext_vector_type(8)));
typedef _Float16 f16x4 __attribute__((ext_vector_type(4)));
typedef float f32x4 __attribute__((ext_vector_type(4)));

#define EDEC_W(v) ((float)((v) >> 17) * (1.f / 32767.f))
#define EDEC_S(v) ((v) & 131071u)

// tanh(x) = (e^2x - 1)/(e^2x + 1); clamp avoids inf*0=NaN.
__device__ __forceinline__ float fast_tanh(float x) {
    float t = __expf(2.f * fminf(x, 15.f));
    return (t - 1.f) * __builtin_amdgcn_rcpf(t + 1.f);
}

// prep: x->fp16; edges packed to 4B (src 17b | w 15b); weights fp16^T; rp.
__global__ __launch_bounds__(256) void prep_all(const float* __restrict__ x,
                                                const int* __restrict__ src,
                                                const int* __restrict__ dst,
                                                const float* __restrict__ w,
                                                const float* __restrict__ W0,
                                                const float* __restrict__ W1,
                                                const float* __restrict__ W2,
                                                __half* __restrict__ xh,
                                                unsigned* __restrict__ ewp,
                                                __half* __restrict__ W0t,
                                                __half* __restrict__ W1t,
                                                __half* __restrict__ W2t,
                                                int* __restrict__ rp) {
    int b = blockIdx.x, tid = threadIdx.x;
    if (b < 6250) {                       // x: 12.8M elems, 8/thread
        int base = (b * 256 + tid) * 8;
        float4 a = *(const float4*)(x + base);
        float4 c = *(const float4*)(x + base + 4);
        __half2 h[4];
        h[0] = __floats2half2_rn(a.x, a.y);
        h[1] = __floats2half2_rn(a.z, a.w);
        h[2] = __floats2half2_rn(c.x, c.y);
        h[3] = __floats2half2_rn(c.z, c.w);
        *(float4*)(xh + base) = *(float4*)h;
    } else if (b < 9375) {                // pack 4 edges/thread
        int i = (b - 6250) * 256 + tid;   // < 800000
        int4 s = ((const int4*)src)[i];
        float4 f = ((const float4*)w)[i];
        uint4 p;
        p.x = (unsigned)s.x | ((unsigned)(f.x * 32767.f + 0.5f) << 17);
        p.y = (unsigned)s.y | ((unsigned)(f.y * 32767.f + 0.5f) << 17);
        p.z = (unsigned)s.z | ((unsigned)(f.z * 32767.f + 0.5f) << 17);
        p.w = (unsigned)s.w | ((unsigned)(f.w * 32767.f + 0.5f) << 17);
        ((uint4*)ewp)[i] = p;
    } else if (b < 9440) {                // W0t,W1t [128][128]; W2t [64][128]
        int i = (b - 9375) * 256 + tid;
        if (i < HH * HH) {
            int c = i >> 7, k = i & 127;
            W0t[i] = __float2half_rn(W0[k * HH + c]);
            W1t[i] = __float2half_rn(W1[k * HH + c]);
        }
        if (i < 64 * HH) {
            int c = i >> 7, k = i & 127;
            W2t[i] = __float2half_rn(c < CC ? W2[k * CC + c] : 0.f);
        }
    } else {                              // rp[i] = lower_bound(dst, i)
        int i = (b - 9440) * 256 + tid;
        if (i > NN) return;
        int lo = 0, hi = EE;
        while (lo < hi) {
            int mid = (lo + hi) >> 1;
            if (dst[mid] < i) lo = mid + 1; else hi = mid;
        }
        rp[i] = lo;
    }
}

// r5 spmm core: wave processes 2 nodes sequentially; 4 lane-groups = 4 edges
// per gather instr, 16 edges/iter. Result rows -> wave-shared LDS tile.
__device__ __forceinline__ void spmm_2nodes(const f16x8* __restrict__ hrow,
                                            const unsigned* __restrict__ ewp,
                                            const int* __restrict__ rp,
                                            int n0, int wave, int l,
                                            _Float16 (* __restrict__ As)[136]) {
    int g = l >> 4, r = l & 15;
#pragma unroll 1
    for (int p = 0; p < 2; ++p) {
        int node = n0 + wave * 2 + p;
        int e0 = __builtin_amdgcn_readfirstlane(rp[node]);
        int e1 = __builtin_amdgcn_readfirstlane(rp[node + 1]);
        float acc[8] = {};
        int e = e0;
        while ((e & 3) && e < e1) {       // peel to 16B alignment of ewp+e
            unsigned v = ewp[e];
            float wk = (g == 0) ? EDEC_W(v) : 0.f;
            f16x8 vv = hrow[(size_t)EDEC_S(v) * 16 + r];
#pragma unroll
            for (int j = 0; j < 8; ++j) acc[j] = fmaf(wk, (float)vv[j], acc[j]);
            ++e;
        }
        int e16 = e + ((e1 - e) & ~15);
#pragma unroll 1
        for (; e < e16; e += 16) {        // group g owns edges e+4g .. e+4g+3
            uint4 pk = *(const uint4*)(ewp + e + 4 * g);
            f16x8 v0 = hrow[(size_t)EDEC_S(pk.x) * 16 + r];
            f16x8 v1 = hrow[(size_t)EDEC_S(pk.y) * 16 + r];
            f16x8 v2 = hrow[(size_t)EDEC_S(pk.z) * 16 + r];
            f16x8 v3 = hrow[(size_t)EDEC_S(pk.w) * 16 + r];
            float w0 = EDEC_W(pk.x), w1 = EDEC_W(pk.y);
            float w2 = EDEC_W(pk.z), w3 = EDEC_W(pk.w);
#pragma unroll
            for (int j = 0; j < 8; ++j) acc[j] = fmaf(w0, (float)v0[j], acc[j]);
#pragma unroll
            for (int j = 0; j < 8; ++j) acc[j] = fmaf(w1, (float)v1[j], acc[j]);
#pragma unroll
            for (int j = 0; j < 8; ++j) acc[j] = fmaf(w2, (float)v2[j], acc[j]);
#pragma unroll
            for (int j = 0; j < 8; ++j) acc[j] = fmaf(w3, (float)v3[j], acc[j]);
        }
        if (e < e1) {                     // masked tail (<16 edges)
#pragma unroll
            for (int k = 0; k < 4; ++k) {
                int idx = e + 4 * g + k;
                bool val = idx < e1;
                unsigned v = ewp[val ? idx : e0];
                float wk = val ? EDEC_W(v) : 0.f;
                f16x8 vv = hrow[(size_t)EDEC_S(v) * 16 + r];
#pragma unroll
                for (int j = 0; j < 8; ++j) acc[j] = fmaf(wk, (float)vv[j], acc[j]);
            }
        }
#pragma unroll
        for (int j = 0; j < 8; ++j) {
            acc[j] += __shfl_xor(acc[j], 16);
            acc[j] += __shfl_xor(acc[j], 32);
        }
        if (l < 16) {
            f16x8 vv;
#pragma unroll
            for (int j = 0; j < 8; ++j) vv[j] = (_Float16)acc[j];
            *(f16x8*)&As[wave * 2 + p][r * 8] = vv;
        }
    }
}

// Layer 1 fused: out = tanh(spmm(xh) @ W0). Block = 16 nodes, 8 waves.
__global__ __launch_bounds__(512, 6) void fused_l1(const __half* __restrict__ h,
                                                   const unsigned* __restrict__ ewp,
                                                   const int* __restrict__ rp,
                                                   const __half* __restrict__ Wt,
                                                   __half* __restrict__ out) {
    __shared__ _Float16 As[16][136];
    __shared__ _Float16 As2[16][136];
    int tid = threadIdx.x, wave = tid >> 6, l = tid & 63;
    int n0 = blockIdx.x * 16;
    spmm_2nodes((const f16x8*)h, ewp, rp, n0, wave, l, As);
    __syncthreads();
    int lr = l & 15, lg = l >> 4;
    const _Float16* Wf = (const _Float16*)Wt;
    {   // wave = ct tile (8 waves x 16 cols = 128 cols)
        f16x8 a[4];
#pragma unroll
        for (int kb = 0; kb < 4; ++kb)
            a[kb] = *(const f16x8*)&As[lr][kb * 32 + lg * 8];
        f32x4 acc = {0.f, 0.f, 0.f, 0.f};
#pragma unroll
        for (int kb = 0; kb < 4; ++kb) {
            f16x8 b = *(const f16x8*)(Wf + (size_t)(wave * 16 + lr) * HH + kb * 32 + lg * 8);
            acc = __builtin_amdgcn_mfma_f32_16x16x32_f16(a[kb], b, acc, 0, 0, 0);
        }
#pragma unroll
        for (int rr = 0; rr < 4; ++rr)
            As2[lg * 4 + rr][wave * 16 + lr] = (_Float16)fast_tanh(acc[rr]);
    }
    __syncthreads();
    int row = wave * 2 + (l >> 5), c = (l & 31) * 4;   // 32 lanes x 8B = 256B row
    f16x4 v = *(const f16x4*)&As2[row][c];
    *(f16x4*)((_Float16*)out + (size_t)(n0 + row) * HH + c) = v;
}

// Layer 2 + projection fused: g = tanh(spmm(hb) @ W1) @ W2 -> [NN][64].
__global__ __launch_bounds__(512, 6) void fused_l2(const __half* __restrict__ h,
                                                   const unsigned* __restrict__ ewp,
                                                   const int* __restrict__ rp,
                                                   const __half* __restrict__ W1t,
                                                   const __half* __restrict__ W2t,
                                                   __half* __restrict__ gout) {
    __shared__ _Float16 As[16][136];
    __shared__ _Float16 As2[16][136];
    int tid = threadIdx.x, wave = tid >> 6, l = tid & 63;
    int n0 = blockIdx.x * 16;
    spmm_2nodes((const f16x8*)h, ewp, rp, n0, wave, l, As);
    __syncthreads();
    int lr = l & 15, lg = l >> 4;
    const _Float16* W1f = (const _Float16*)W1t;
    const _Float16* W2f = (const _Float16*)W2t;
    {   // GEMM1: h2 tile = tanh(As @ W1)
        f16x8 a[4];
#pragma unroll
        for (int kb = 0; kb < 4; ++kb)
            a[kb] = *(const f16x8*)&As[lr][kb * 32 + lg * 8];
        f32x4 acc = {0.f, 0.f, 0.f, 0.f};
#pragma unroll
        for (int kb = 0; kb < 4; ++kb) {
            f16x8 b = *(const f16x8*)(W1f + (size_t)(wave * 16 + lr) * HH + kb * 32 + lg * 8);
            acc = __builtin_amdgcn_mfma_f32_16x16x32_f16(a[kb], b, acc, 0, 0, 0);
        }
#pragma unroll
        for (int rr = 0; rr < 4; ++rr)
            As2[lg * 4 + rr][wave * 16 + lr] = (_Float16)fast_tanh(acc[rr]);
    }
    __syncthreads();
    if (wave < 4) {   // GEMM2: g tile = As2 @ W2 (64 cols)
        f16x8 a[4];
#pragma unroll
        for (int kb = 0; kb < 4; ++kb)
            a[kb] = *(const f16x8*)&As2[lr][kb * 32 + lg * 8];
        f32x4 acc = {0.f, 0.f, 0.f, 0.f};
#pragma unroll
        for (int kb = 0; kb < 4; ++kb) {
            f16x8 b = *(const f16x8*)(W2f + (size_t)(wave * 16 + lr) * HH + kb * 32 + lg * 8);
            acc = __builtin_amdgcn_mfma_f32_16x16x32_f16(a[kb], b, acc, 0, 0, 0);
        }
#pragma unroll
        for (int rr = 0; rr < 4; ++rr)
            As[lg * 4 + rr][wave * 16 + lr] = (_Float16)acc[rr];
    }
    __syncthreads();
    if (wave < 4) {   // 16 rows x 128B, 16 lanes x 8B per row
        int row = wave * 4 + (l >> 4);
        int c = (l & 15) * 4;
        f16x4 v = *(const f16x4*)&As[row][c];
        *(f16x4*)((_Float16*)gout + (size_t)(n0 + row) * 64 + c) = v;
    }
}

// Layer 3: out = tanh(spmm(g)); g rows padded to 64 halves (128B). 8 lanes/row.
__global__ __launch_bounds__(256) void spmm40_tanh(const __half* __restrict__ gpad,
                                                   const unsigned* __restrict__ ewp,
                                                   const int* __restrict__ rp,
                                                   float* __restrict__ out) {
    int node = blockIdx.x * 4 + (threadIdx.x >> 6);
    int l = threadIdx.x & 63;
    if (node >= NN) return;
    int e0 = __builtin_amdgcn_readfirstlane(rp[node]);
    int e1 = __builtin_amdgcn_readfirstlane(rp[node + 1]);
    int g = l >> 3, r = l & 7;
    const f16x8* __restrict__ grw = (const f16x8*)gpad;
    float acc[8] = {};
    int e = e0;
    while ((e & 1) && e < e1) {           // peel to 8B alignment
        unsigned v = ewp[e];
        float wk = (g == 0) ? EDEC_W(v) : 0.f;
        f16x8 vv = grw[(size_t)EDEC_S(v) * 8 + r];
#pragma unroll
        for (int j = 0; j < 8; ++j) acc[j] = fmaf(wk, (float)vv[j], acc[j]);
        ++e;
    }
    int e16 = e + ((e1 - e) & ~15);
    for (; e < e16; e += 16) {            // group g owns edges e+2g, e+2g+1
        uint2 pa = *(const uint2*)(ewp + e + 2 * g);
        f16x8 v0 = grw[(size_t)EDEC_S(pa.x) * 8 + r];
        f16x8 v1 = grw[(size_t)EDEC_S(pa.y) * 8 + r];
        float w0 = EDEC_W(pa.x), w1 = EDEC_W(pa.y);
#pragma unroll
        for (int j = 0; j < 8; ++j) acc[j] = fmaf(w0, (float)v0[j], acc[j]);
#pragma unroll
        for (int j = 0; j < 8; ++j) acc[j] = fmaf(w1, (float)v1[j], acc[j]);
    }
    if (e < e1) {                         // masked tail (<16 edges)
#pragma unroll
        for (int k = 0; k < 2; ++k) {
            int idx = e + 2 * g + k;
            bool val = idx < e1;
            unsigned v = ewp[val ? idx : e0];
            float wk = val ? EDEC_W(v) : 0.f;
            f16x8 vv = grw[(size_t)EDEC_S(v) * 8 + r];
#pragma unroll
            for (int j = 0; j < 8; ++j) acc[j] = fmaf(wk, (float)vv[j], acc[j]);
        }
    }
#pragma unroll
    for (int j = 0; j < 8; ++j) {
        acc[j] += __shfl_xor(acc[j], 8);
        acc[j] += __shfl_xor(acc[j], 16);
        acc[j] += __shfl_xor(acc[j], 32);
    }
    if (l < 5) {
        float o[8];
#pragma unroll
        for (int j = 0; j < 8; ++j) o[j] = fast_tanh(acc[j]);
        *(float4*)(out + (size_t)node * CC + r * 8) = *(float4*)&o[0];
        *(float4*)(out + (size_t)node * CC + r * 8 + 4) = *(float4*)&o[4];
    }
}

extern "C" void kernel_launch(void* const* d_in, const int* in_sizes, int n_in,
                              void* d_out, int out_size, void* d_ws, size_t ws_size,
                              hipStream_t stream) {
    const float* x    = (const float*)d_in[0];
    const int*   esrc = (const int*)d_in[1];
    const int*   edst = (const int*)d_in[2];
    const float* ew_f = (const float*)d_in[3];
    const float* W0   = (const float*)d_in[4];
    const float* W1   = (const float*)d_in[5];
    const float* W2   = (const float*)d_in[6];
    float* out = (float*)d_out;

    char* ws = (char*)d_ws;
    size_t off = 0;
    int* rp = (int*)(ws + off);            off += (((size_t)(NN + 1) * 4) + 511) & ~(size_t)511;
    __half* buf0 = (__half*)(ws + off);    off += (size_t)NN * HH * sizeof(__half); // xh, later g
    __half* hb = (__half*)(ws + off);      off += (size_t)NN * HH * sizeof(__half);
    unsigned* ewp = (unsigned*)(ws + off); off += (size_t)EE * sizeof(unsigned);
    __half* W0t = (__half*)(ws + off);     off += (size_t)HH * HH * sizeof(__half);
    __half* W1t = (__half*)(ws + off);     off += (size_t)HH * HH * sizeof(__half);
    __half* W2t = (__half*)(ws + off);     off += (size_t)64 * HH * sizeof(__half);
    __half* xh = buf0;
    __half* gb = buf0;  // alias: xh dead after fused_l1

    // 6250 x-convert + 3125 edge-pack + 65 weights + 392 rp = 9832 blocks
    prep_all<<<9832, 256, 0, stream>>>(x, esrc, edst, ew_f, W0, W1, W2,
                                       xh, ewp, W0t, W1t, W2t, rp);

    fused_l1<<<NN / 16, 512, 0, stream>>>(xh, ewp, rp, W0t, hb);
    fused_l2<<<NN / 16, 512, 0, stream>>>(hb, ewp, rp, W1t, W2t, gb);
    spmm40_tanh<<<NN / 4, 256, 0, stream>>>(gb, ewp, rp, out);
}